// Round 2
// baseline (168.125 us; speedup 1.0000x reference)
//
#include <hip/hip_runtime.h>
#include <math.h>

#define H 256
#define N2 32
#define Bsz 8
#define Lseq 4096
#define BH (Bsz*H)          // 2048 sequences
#define NCH 32              // chunks along L
#define LC (Lseq/NCH)       // 128 chunk length
#define HN (H*N2)           // 8192

// workspace layout (float slots):
//  yb : BH*Lseq bf16        post-GELU activations
//  Wb : 512*256 bf16        pre-converted W
//  Tb : H*128*128 bf16      Toeplitz conv matrix T[h][j][m] = k[h][j-m] (0 if j<m)
//  Eb : H*128*64 bf16       emission basis E[h][j][p]   (j-major, p-contig)
//  Vb : H*64*128 bf16       state basis  V[h][p][j]     (p-major, j-contig)
#define Y_OFF  0
#define WB_OFF (Y_OFF + (BH*Lseq/2))
#define TB_OFF (WB_OFF + (512*256/2))
#define EB_OFF (TB_OFF + (H*128*128/2))
#define VB_OFF (EB_OFF + (H*128*64/2))

typedef __attribute__((ext_vector_type(8))) short bf16x8;
typedef __attribute__((ext_vector_type(8))) unsigned short u16x8;
typedef __attribute__((ext_vector_type(4))) float f32x4;

__device__ __forceinline__ unsigned short f2bf(float x) {
  union { float f; unsigned int u; } v; v.f = x;
  unsigned int r = v.u + 0x7fffu + ((v.u >> 16) & 1u);  // round-to-nearest-even
  return (unsigned short)(r >> 16);
}
__device__ __forceinline__ unsigned int packbf(float lo, float hi) {
  return (unsigned int)f2bf(lo) | ((unsigned int)f2bf(hi) << 16);
}
__device__ __forceinline__ float bf2f(unsigned short b) {
  union { unsigned int u; float f; } v; v.u = ((unsigned int)b) << 16;
  return v.f;
}

// ---------------- K0: prep — W->bf16, Toeplitz Tb, bases Eb & Vb ----------------
// grid 256 (h), block 512 = (j 0..127) x (ng 0..3); each ng-group handles 8 of the
// 32 complex modes. 8 waves/block = 2 waves/SIMD: the serial transcendental chains
// (expf/sincosf dependency chains) are latency-bound; doubling resident waves/SIMD
// halves exposed latency (was 1/SIMD at 256 threads).
__global__ __launch_bounds__(512) void k_prep(const float* __restrict__ log_dt,
                                              const float* __restrict__ C,
                                              const float* __restrict__ lar,
                                              const float* __restrict__ aim,
                                              const float* __restrict__ W,
                                              unsigned short* __restrict__ Wb,
                                              unsigned short* __restrict__ Tb,
                                              unsigned short* __restrict__ Eb,
                                              unsigned short* __restrict__ Vb) {
  __shared__ float kpart[3][128];
  __shared__ unsigned short kbuf[128];
  int h   = blockIdx.x;
  int tid = threadIdx.x;
  int j   = tid & 127;                       // position in chunk
  int ng  = tid >> 7;                        // n-group {0..3}
  // ---- W fp32 -> bf16: threads 0..127 convert one float4 each (128*256 = all of W/4) ----
  if (tid < 128) {
    int i = h * 128 + tid;
    float4 v = *(const float4*)&W[i * 4];
    uint2 p; p.x = packbf(v.x, v.y); p.y = packbf(v.z, v.w);
    *(uint2*)&Wb[i * 4] = p;
  }
  float dt = expf(log_dt[h]);
  float kacc = 0.f;
  unsigned short* Erow = Eb + (h * 128 + j) * 64;
  for (int nn = 0; nn < 8; nn++) {
    int n  = ng * 8 + nn;
    int hn = (h << 5) + n;
    float Ar = -expf(lar[hn]), Ai = aim[hn];
    float dAr = Ar * dt, dAi = Ai * dt;
    float er = expf(dAr), sw, cw;
    sincosf(dAi, &sw, &cw);
    float wr = er * cw, wi = er * sw;
    float emr = wr - 1.f, emi = wi;
    float inv = 1.f / (Ar * Ar + Ai * Ai);
    float qr = (emr * Ar + emi * Ai) * inv;
    float qi = (emi * Ar - emr * Ai) * inv;
    float Cr = C[2 * hn], Ci = C[2 * hn + 1];
    float c2r = 2.f * (Cr * qr - Ci * qi);    // 2*Ct
    float c2i = 2.f * (Cr * qi + Ci * qr);
    // k[j] += Re(2Ct * w^j)
    float ej = expf(dAr * (float)j), sj, cj;
    sincosf(dAi * (float)j, &sj, &cj);
    kacc = fmaf(c2r, ej * cj, fmaf(-c2i, ej * sj, kacc));
    // E[j][2n] = Re(2Ct w^{j+1}), E[j][2n+1] = -Im(2Ct w^{j+1})
    float e1 = expf(dAr * (float)(j + 1)), s1, c1;
    sincosf(dAi * (float)(j + 1), &s1, &c1);
    float w1r = e1 * c1, w1i = e1 * s1;
    Erow[2 * n]     = f2bf(c2r * w1r - c2i * w1i);
    Erow[2 * n + 1] = f2bf(-(c2r * w1i + c2i * w1r));
    // V[2n][j] = Re(w^{127-j}), V[2n+1][j] = Im(w^{127-j})
    float ev = expf(dAr * (float)(127 - j)), sv, cv;
    sincosf(dAi * (float)(127 - j), &sv, &cv);
    Vb[(h * 64 + 2 * n) * 128 + j]     = f2bf(ev * cv);
    Vb[(h * 64 + 2 * n + 1) * 128 + j] = f2bf(ev * sv);
  }
  if (ng) kpart[ng - 1][j] = kacc;
  __syncthreads();
  if (ng == 0) kbuf[j] = f2bf(kacc + kpart[0][j] + kpart[1][j] + kpart[2][j]);
  __syncthreads();
  // Toeplitz row j: Tb[h][j][m] = kbuf[j-m] (j>=m) else 0; ng-groups split the 16 chunks
  unsigned short* Trow = Tb + (h * 128 + j) * 128;
#pragma unroll
  for (int s8i = 0; s8i < 4; s8i++) {
    int s8 = ng * 4 + s8i;
    u16x8 v;
#pragma unroll
    for (int t = 0; t < 8; t++) {
      int m = s8 * 8 + t;
      v[t] = (j >= m) ? kbuf[j - m] : (unsigned short)0;
    }
    *(u16x8*)&Trow[s8 * 8] = v;
  }
}

// ---------------- K1: fused SSM: states + prefix + emit, one block per (b,h) ----------------
// Block = 256 thr = 4 waves.
//  - A-fragments (u in bf16) loaded DIRECT from global into registers: the MFMA
//    A-layout (lane&15 = row c, quad*8 = k-offset, 8 k-contig) means one fragment =
//    two float4 loads/lane; per-instruction the wave covers 16 rows x 128B contiguous
//    segments (perfect coalescing). Same 8 fragments feed BOTH the state GEMM and the
//    first 128-K of the emit GEMM -> u read once, no Ub LDS stage, no phase-1 barrier.
//  - phases: load av + state GEMM (barrier-free) -> Fb -> prefix -> Fl -> emit GEMM
//    (av regs + Fl LDS) -> epilogue (u re-read from L1, tanh-GELU).
//
// XCD mapping: workgroup -> XCD is blockIdx % 8 on MI355X. With h = g & 255,
// g mod 8 == h mod 8, so all 8 batch-copies of a given h land on the SAME XCD:
// per-XCD T/E/V working set = 32 h * 64KB = 2MB (fits the 4MB L2).
__global__ __launch_bounds__(256) void k_ssm(const float* __restrict__ u,
                                             const float* __restrict__ log_dt,
                                             const float* __restrict__ lar,
                                             const float* __restrict__ aim,
                                             const unsigned short* __restrict__ Vb,
                                             const unsigned short* __restrict__ Tb,
                                             const unsigned short* __restrict__ Eb,
                                             const float* __restrict__ Dp,
                                             unsigned short* __restrict__ yb) {
  __shared__ float          Fb[32][68];    // chunk-final states (fp32)
  __shared__ unsigned short Fl[32][72];    // incoming states (bf16), row stride 144 B
  int g   = blockIdx.x;
  int h   = g & 255, b = g >> 8;           // same-h blocks share an XCD -> T/E/V L2 reuse
  int tid = threadIdx.x;
  int wv = tid >> 6, lane = tid & 63;
  int n16 = lane & 15, quad = lane >> 4;
  const float* ubase = u + (b * 256 + h) * 4096;

  // ---- load A-fragments (u) direct from global into regs ----
  bf16x8 av[4][2];                          // [ks/32][mt]
#pragma unroll
  for (int ksi = 0; ksi < 4; ksi++) {
#pragma unroll
    for (int mt = 0; mt < 2; mt++) {
      const float* p = ubase + (mt * 16 + n16) * 128 + ksi * 32 + quad * 8;
      float4 a4 = *(const float4*)p;
      float4 b4 = *(const float4*)(p + 4);
      union { bf16x8 v; unsigned int w[4]; } t;
      t.w[0] = packbf(a4.x, a4.y); t.w[1] = packbf(a4.z, a4.w);
      t.w[2] = packbf(b4.x, b4.y); t.w[3] = packbf(b4.z, b4.w);
      av[ksi][mt] = t.v;
    }
  }

  // ---- phase 2: state GEMM (M=32 c, N=64 p, K=128 j); wave wv owns p-tile wv ----
  {
    f32x4 sacc[2] = {};
#pragma unroll
    for (int ksi = 0; ksi < 4; ksi++) {
      int kc = ksi * 32 + quad * 8;
      bf16x8 bv = *(const bf16x8*)&Vb[(h * 64 + wv * 16 + n16) * 128 + kc];
#pragma unroll
      for (int mt = 0; mt < 2; mt++)
        sacc[mt] = __builtin_amdgcn_mfma_f32_16x16x32_bf16(av[ksi][mt], bv, sacc[mt], 0, 0, 0);
    }
#pragma unroll
    for (int mt = 0; mt < 2; mt++)
#pragma unroll
      for (int reg = 0; reg < 4; reg++)
        Fb[mt * 16 + quad * 4 + reg][wv * 16 + n16] = sacc[mt][reg];
  }
  __syncthreads();

  // ---- phase 3: serial prefix (wave 0, lane n = complex pair) ----
  if (wv == 0 && lane < 32) {
    int n = lane, hn = (h << 5) + n;
    float dt  = expf(log_dt[h]);
    float dAr = -expf(lar[hn]) * dt, dAi = aim[hn] * dt;
    float eL = expf(dAr * (float)LC), sL, cL;
    sincosf(dAi * (float)LC, &sL, &cL);
    float wLr = eL * cL, wLi = eL * sL;
    float fr = 0.f, fi = 0.f;
    for (int c = 0; c < NCH; c++) {
      float sr = Fb[c][2 * n], si = Fb[c][2 * n + 1];
      *(unsigned int*)&Fl[c][2 * n] = packbf(fr, fi);   // incoming state for chunk c
      float nr = fmaf(wLr, fr, fmaf(-wLi, fi, sr));
      float ni = fmaf(wLr, fi, fmaf(wLi, fr, si));
      fr = nr; fi = ni;
    }
  }
  __syncthreads();

  // ---- phase 4: emit GEMM (M=32 c, N=128 j, K=192 [u|F]); wave wv owns j-tiles 2wv,2wv+1 ----
  f32x4 acc[2][2] = {};                     // [mt][ntl]
#pragma unroll
  for (int ksi = 0; ksi < 6; ksi++) {
    int kc = ksi * 32 + quad * 8;
    bf16x8 a2[2];
#pragma unroll
    for (int mt = 0; mt < 2; mt++)
      a2[mt] = (ksi < 4) ? av[ksi][mt]
                         : *(const bf16x8*)&Fl[mt * 16 + n16][kc - 128];
#pragma unroll
    for (int ntl = 0; ntl < 2; ntl++) {
      int j = (wv * 2 + ntl) * 16 + n16;
      bf16x8 bv = (ksi < 4) ? *(const bf16x8*)&Tb[(h * 128 + j) * 128 + kc]
                            : *(const bf16x8*)&Eb[(h * 128 + j) * 64 + kc - 128];
#pragma unroll
      for (int mt = 0; mt < 2; mt++)
        acc[mt][ntl] = __builtin_amdgcn_mfma_f32_16x16x32_bf16(a2[mt], bv, acc[mt][ntl], 0, 0, 0);
    }
  }

  // ---- phase 5: epilogue — skip, tanh-GELU (== v*sigmoid(2t)), store bf16 ----
  float Dh = Dp[h];
  unsigned short* ybase = yb + (b * 256 + h) * 4096;
#pragma unroll
  for (int mt = 0; mt < 2; mt++) {
#pragma unroll
    for (int reg = 0; reg < 4; reg++) {
      int c = mt * 16 + quad * 4 + reg;
#pragma unroll
      for (int ntl = 0; ntl < 2; ntl++) {
        int j = (wv * 2 + ntl) * 16 + n16;
        float uv = ubase[c * 128 + j];          // L1-hot (block just streamed these 16KB)
        float v  = fmaf(Dh, uv, acc[mt][ntl][reg]);
        // tanh-GELU: 0.5v(1+tanh(t)) = v*sigmoid(2t), t = 0.79788456*v*(1+0.044715 v^2)
        float t2 = 1.5957691216057308f * v * fmaf(0.044715f, v * v, 1.0f);
        float ge = v / (1.0f + expf(-t2));
        ybase[c * 128 + j] = f2bf(ge);
      }
    }
  }
}

// ---------------- K4: MFMA bf16 GEMM: z = W@y + b ; out = a * sigmoid(g) ----------------
// A-operand (W) read DIRECT from global per fragment: Wb is 256KB, L2-resident and
// shared by all blocks on the XCD -> no Ws LDS stage. Ys double-buffered: y loads for
// the next K-step are issued right after the barrier and land in registers while MFMA
// runs on the current buffer (T14-lite); ONE barrier per K-step (dbuf: the buffer
// written at step k+1 was last read at step k-1, ordered by barrier k).
// XCD note: blocks sharing a y-tile (same bb/l0, different o0) differ by 32 in linear
// id => same (id mod 8) => same XCD.
__global__ __launch_bounds__(256) void k_gemm(const unsigned short* __restrict__ yb,
                                              const unsigned short* __restrict__ Wb,
                                              const float* __restrict__ bias,
                                              float* __restrict__ out) {
  __shared__ unsigned short Ys[2][128][72];
  int tid  = threadIdx.x;
  int l0   = blockIdx.x * 128;
  int o0   = blockIdx.y * 64;
  int bb   = blockIdx.z;
  int wave = tid >> 6;
  int lane = tid & 63;
  int wo   = wave & 1;
  int wl   = wave >> 1;
  int n    = lane & 15;
  int quad = lane >> 4;
  int kcol = tid & 63;
  int lg0  = tid >> 6;

  f32x4 acc_a[2][4] = {};
  f32x4 acc_g[2][4] = {};

  u16x8 yreg[4];
  {
    const unsigned short* yr = yb + (size_t)(bb * 256 + kcol) * 4096 + l0;
#pragma unroll
    for (int i = 0; i < 4; i++)
      yreg[i] = *(const u16x8*)&yr[(lg0 * 4 + i) * 8];
  }

#pragma unroll
  for (int kk = 0; kk < H; kk += 64) {
    int cur = (kk >> 6) & 1;
    // transpose-write staged regs into Ys[cur]
#pragma unroll
    for (int i = 0; i < 4; i++) {
      int l8 = (lg0 * 4 + i) * 8;
#pragma unroll
      for (int jj = 0; jj < 8; jj++)
        Ys[cur][l8 + jj][kcol] = yreg[i][jj];
    }
    __syncthreads();
    // issue next K-step's y loads; HBM/L2 latency hides under the MFMAs below
    if (kk + 64 < H) {
      const unsigned short* yr = yb + (size_t)(bb * 256 + kk + 64 + kcol) * 4096 + l0;
#pragma unroll
      for (int i = 0; i < 4; i++)
        yreg[i] = *(const u16x8*)&yr[(lg0 * 4 + i) * 8];
    }
#pragma unroll
    for (int ks = 0; ks < 64; ks += 32) {
      int kc = ks + quad * 8;
      bf16x8 af_a[2], af_g[2], bfr[4];
#pragma unroll
      for (int mt = 0; mt < 2; mt++) {
        int oa = o0 + wo * 32 + mt * 16 + n;
        af_a[mt] = *(const bf16x8*)&Wb[(size_t)oa * 256 + kk + kc];
        af_g[mt] = *(const bf16x8*)&Wb[(size_t)(256 + oa) * 256 + kk + kc];
      }
#pragma unroll
      for (int lt = 0; lt < 4; lt++)
        bfr[lt] = *(const bf16x8*)&Ys[cur][wl * 64 + lt * 16 + n][kc];
#pragma unroll
      for (int mt = 0; mt < 2; mt++)
#pragma unroll
        for (int lt = 0; lt < 4; lt++) {
          acc_a[mt][lt] = __builtin_amdgcn_mfma_f32_16x16x32_bf16(af_a[mt], bfr[lt], acc_a[mt][lt], 0, 0, 0);
          acc_g[mt][lt] = __builtin_amdgcn_mfma_f32_16x16x32_bf16(af_g[mt], bfr[lt], acc_g[mt][lt], 0, 0, 0);
        }
    }
  }
#pragma unroll
  for (int mt = 0; mt < 2; mt++) {
    int ob = o0 + wo * 32 + mt * 16 + quad * 4;
#pragma unroll
    for (int reg = 0; reg < 4; reg++) {
      int op = ob + reg;
      float ba = bias[op], bg = bias[H + op];
      float* orow = &out[(bb * H + op) * Lseq + l0 + wl * 64 + n];
#pragma unroll
      for (int lt = 0; lt < 4; lt++) {
        float a = acc_a[mt][lt][reg] + ba;
        float gg = acc_g[mt][lt][reg] + bg;
        orow[lt * 16] = a / (1.0f + expf(-gg));
      }
    }
  }
}

extern "C" void kernel_launch(void* const* d_in, const int* in_sizes, int n_in,
                              void* d_out, int out_size, void* d_ws, size_t ws_size,
                              hipStream_t stream) {
  const float* u      = (const float*)d_in[0];
  const float* log_dt = (const float*)d_in[1];
  const float* C      = (const float*)d_in[2];
  const float* lar    = (const float*)d_in[3];
  const float* aim    = (const float*)d_in[4];
  const float* Dp     = (const float*)d_in[5];
  const float* W      = (const float*)d_in[6];
  const float* bias   = (const float*)d_in[7];
  float* out = (float*)d_out;
  float* ws  = (float*)d_ws;
  unsigned short* yb  = (unsigned short*)(ws + Y_OFF);
  unsigned short* Wb  = (unsigned short*)(ws + WB_OFF);
  unsigned short* Tbg = (unsigned short*)(ws + TB_OFF);
  unsigned short* Ebg = (unsigned short*)(ws + EB_OFF);
  unsigned short* Vbg = (unsigned short*)(ws + VB_OFF);

  hipLaunchKernelGGL(k_prep, dim3(H), dim3(512), 0, stream, log_dt, C, lar, aim, W, Wb, Tbg, Ebg, Vbg);
  hipLaunchKernelGGL(k_ssm,  dim3(BH), dim3(256), 0, stream, u, log_dt, lar, aim, Vbg, Tbg, Ebg, Dp, yb);
  hipLaunchKernelGGL(k_gemm, dim3(Lseq / 128, H / 64, Bsz), dim3(256), 0, stream, yb, Wb, bias, out);
}

// Round 3
// 154.925 us; speedup vs baseline: 1.0852x; 1.0852x over previous
//
#include <hip/hip_runtime.h>
#include <math.h>

#define H 256
#define N2 32
#define Bsz 8
#define Lseq 4096
#define BH (Bsz*H)          // 2048 sequences
#define NCH 32              // chunks along L
#define LC (Lseq/NCH)       // 128 chunk length
#define HN (H*N2)           // 8192

// workspace layout (float slots):
//  yb : BH*Lseq bf16        post-GELU activations
//  Wb : 512*256 bf16        pre-converted W
//  Tb : H*128*128 bf16      Toeplitz conv matrix T[h][j][m] = k[h][j-m] (0 if j<m)
//  Eb : H*128*64 bf16       emission basis E[h][j][p]   (j-major, p-contig)
//  Vb : H*64*128 bf16       state basis  V[h][p][j]     (p-major, j-contig)
#define Y_OFF  0
#define WB_OFF (Y_OFF + (BH*Lseq/2))
#define TB_OFF (WB_OFF + (512*256/2))
#define EB_OFF (TB_OFF + (H*128*128/2))
#define VB_OFF (EB_OFF + (H*128*64/2))

typedef __attribute__((ext_vector_type(8))) short bf16x8;
typedef __attribute__((ext_vector_type(8))) unsigned short u16x8;
typedef __attribute__((ext_vector_type(4))) float f32x4;

__device__ __forceinline__ unsigned short f2bf(float x) {
  union { float f; unsigned int u; } v; v.f = x;
  unsigned int r = v.u + 0x7fffu + ((v.u >> 16) & 1u);  // round-to-nearest-even
  return (unsigned short)(r >> 16);
}
__device__ __forceinline__ unsigned int packbf(float lo, float hi) {
  return (unsigned int)f2bf(lo) | ((unsigned int)f2bf(hi) << 16);
}
__device__ __forceinline__ float bf2f(unsigned short b) {
  union { unsigned int u; float f; } v; v.u = ((unsigned int)b) << 16;
  return v.f;
}

// ---------------- K0: prep — W->bf16, Toeplitz Tb, bases Eb & Vb ----------------
// grid 256 (h), block 512 = (j 0..127) x (ng 0..3); 8 waves/block = 2 waves/SIMD
// to hide the serial transcendental chains.
__global__ __launch_bounds__(512) void k_prep(const float* __restrict__ log_dt,
                                              const float* __restrict__ C,
                                              const float* __restrict__ lar,
                                              const float* __restrict__ aim,
                                              const float* __restrict__ W,
                                              unsigned short* __restrict__ Wb,
                                              unsigned short* __restrict__ Tb,
                                              unsigned short* __restrict__ Eb,
                                              unsigned short* __restrict__ Vb) {
  __shared__ float kpart[3][128];
  __shared__ unsigned short kbuf[128];
  int h   = blockIdx.x;
  int tid = threadIdx.x;
  int j   = tid & 127;                       // position in chunk
  int ng  = tid >> 7;                        // n-group {0..3}
  // ---- W fp32 -> bf16: threads 0..127 convert one float4 each ----
  if (tid < 128) {
    int i = h * 128 + tid;
    float4 v = *(const float4*)&W[i * 4];
    uint2 p; p.x = packbf(v.x, v.y); p.y = packbf(v.z, v.w);
    *(uint2*)&Wb[i * 4] = p;
  }
  float dt = expf(log_dt[h]);
  float kacc = 0.f;
  unsigned short* Erow = Eb + (h * 128 + j) * 64;
  for (int nn = 0; nn < 8; nn++) {
    int n  = ng * 8 + nn;
    int hn = (h << 5) + n;
    float Ar = -expf(lar[hn]), Ai = aim[hn];
    float dAr = Ar * dt, dAi = Ai * dt;
    float er = expf(dAr), sw, cw;
    sincosf(dAi, &sw, &cw);
    float wr = er * cw, wi = er * sw;
    float emr = wr - 1.f, emi = wi;
    float inv = 1.f / (Ar * Ar + Ai * Ai);
    float qr = (emr * Ar + emi * Ai) * inv;
    float qi = (emi * Ar - emr * Ai) * inv;
    float Cr = C[2 * hn], Ci = C[2 * hn + 1];
    float c2r = 2.f * (Cr * qr - Ci * qi);    // 2*Ct
    float c2i = 2.f * (Cr * qi + Ci * qr);
    // k[j] += Re(2Ct * w^j)
    float ej = expf(dAr * (float)j), sj, cj;
    sincosf(dAi * (float)j, &sj, &cj);
    kacc = fmaf(c2r, ej * cj, fmaf(-c2i, ej * sj, kacc));
    // E[j][2n] = Re(2Ct w^{j+1}), E[j][2n+1] = -Im(2Ct w^{j+1})
    float e1 = expf(dAr * (float)(j + 1)), s1, c1;
    sincosf(dAi * (float)(j + 1), &s1, &c1);
    float w1r = e1 * c1, w1i = e1 * s1;
    Erow[2 * n]     = f2bf(c2r * w1r - c2i * w1i);
    Erow[2 * n + 1] = f2bf(-(c2r * w1i + c2i * w1r));
    // V[2n][j] = Re(w^{127-j}), V[2n+1][j] = Im(w^{127-j})
    float ev = expf(dAr * (float)(127 - j)), sv, cv;
    sincosf(dAi * (float)(127 - j), &sv, &cv);
    Vb[(h * 64 + 2 * n) * 128 + j]     = f2bf(ev * cv);
    Vb[(h * 64 + 2 * n + 1) * 128 + j] = f2bf(ev * sv);
  }
  if (ng) kpart[ng - 1][j] = kacc;
  __syncthreads();
  if (ng == 0) kbuf[j] = f2bf(kacc + kpart[0][j] + kpart[1][j] + kpart[2][j]);
  __syncthreads();
  // Toeplitz row j: Tb[h][j][m] = kbuf[j-m] (j>=m) else 0; ng-groups split the 16 chunks
  unsigned short* Trow = Tb + (h * 128 + j) * 128;
#pragma unroll
  for (int s8i = 0; s8i < 4; s8i++) {
    int s8 = ng * 4 + s8i;
    u16x8 v;
#pragma unroll
    for (int t = 0; t < 8; t++) {
      int m = s8 * 8 + t;
      v[t] = (j >= m) ? kbuf[j - m] : (unsigned short)0;
    }
    *(u16x8*)&Trow[s8 * 8] = v;
  }
}

// ---------------- K1: fused SSM: states + prefix + emit, one block per (b,h) ----------------
// Block = 256 thr = 4 waves. R1-proven structure (LDS-staged Ub) + two changes:
//  * Fl merged INTO Fb: the prefix writes the packed bf16 incoming state in place
//    into the fp32 slot it just read (read-before-write; per-wave in-order LDS;
//    sched_barrier(0) pins compiler order). LDS 22016 -> 17408 B.
//  * __launch_bounds__(256, 8) pins VGPR<=64 so 8 waves/SIMD fit: with the grid at
//    exactly 8 blocks/CU, ALL blocks are co-resident (was 7/CU -> ~8/7 rounds of a
//    latency-dominated block).
// Phases: stage u -> state GEMM -> Fb -> prefix (packed in place) -> emit GEMM
//         (Ub + Fb-packed A, Tb/Eb B direct from L2) -> tanh-GELU epilogue.
// XCD mapping: h = g & 255 => g mod 8 == h mod 8: all 8 batch-copies of an h share
// an XCD; per-XCD T/E/V working set = 2MB (L2-resident, warm from k_prep).
__global__ __launch_bounds__(256, 8) void k_ssm(const float* __restrict__ u,
                                             const float* __restrict__ log_dt,
                                             const float* __restrict__ lar,
                                             const float* __restrict__ aim,
                                             const unsigned short* __restrict__ Vb,
                                             const unsigned short* __restrict__ Tb,
                                             const unsigned short* __restrict__ Eb,
                                             const float* __restrict__ Dp,
                                             unsigned short* __restrict__ yb) {
  __shared__ __align__(16) unsigned short Ub[32][136];  // row stride 272 B (17*16)
  __shared__ __align__(16) float          Fb[32][68];   // fp32 chunk-final states;
                                                        // cols 0..31 become packed bf16
                                                        // incoming states after prefix
  int g   = blockIdx.x;
  int h   = g & 255, b = g >> 8;           // same-h blocks share an XCD -> T/E/V L2 reuse
  int tid = threadIdx.x;
  int wv = tid >> 6, lane = tid & 63;
  int n16 = lane & 15, quad = lane >> 4;
  const float* ubase = u + (b * 256 + h) * 4096;

  // ---- phase 1: stage u (coalesced float4 pairs -> bf16 LDS) ----
#pragma unroll
  for (int i = 0; i < 2; i++) {
    int idx = tid * 2 + i;                  // 0..511 float8s
    float4 va = *(const float4*)(ubase + idx * 8);
    float4 vb4 = *(const float4*)(ubase + idx * 8 + 4);
    unsigned short* dst = &Ub[idx >> 4][(idx & 15) * 8];
    *(unsigned int*)(dst)     = packbf(va.x, va.y);
    *(unsigned int*)(dst + 2) = packbf(va.z, va.w);
    *(unsigned int*)(dst + 4) = packbf(vb4.x, vb4.y);
    *(unsigned int*)(dst + 6) = packbf(vb4.z, vb4.w);
  }
  __syncthreads();

  // ---- phase 2: state GEMM (M=32 c, N=64 p, K=128 j); wave wv owns p-tile wv ----
  {
    f32x4 sacc[2] = {};
#pragma unroll
    for (int ks = 0; ks < 128; ks += 32) {
      int kc = ks + quad * 8;
      bf16x8 bv = *(const bf16x8*)&Vb[(h * 64 + wv * 16 + n16) * 128 + kc];
#pragma unroll
      for (int mt = 0; mt < 2; mt++) {
        bf16x8 av = *(const bf16x8*)&Ub[mt * 16 + n16][kc];
        sacc[mt] = __builtin_amdgcn_mfma_f32_16x16x32_bf16(av, bv, sacc[mt], 0, 0, 0);
      }
    }
#pragma unroll
    for (int mt = 0; mt < 2; mt++)
#pragma unroll
      for (int reg = 0; reg < 4; reg++)
        Fb[mt * 16 + quad * 4 + reg][wv * 16 + n16] = sacc[mt][reg];
  }
  __syncthreads();

  // ---- phase 3: serial prefix (wave 0, lane n = complex pair), packed IN PLACE ----
  // Reads fp32 state at cols {2n,2n+1}, then overwrites col n with the packed bf16
  // incoming state (fr,fi). Read precedes write in program order; LDS ops from one
  // wave complete in order; sched_barrier(0) stops the compiler from reordering the
  // type-punned store above the reads.
  if (wv == 0 && lane < 32) {
    int n = lane, hn = (h << 5) + n;
    float dt  = expf(log_dt[h]);
    float dAr = -expf(lar[hn]) * dt, dAi = aim[hn] * dt;
    float eL = expf(dAr * (float)LC), sL, cL;
    sincosf(dAi * (float)LC, &sL, &cL);
    float wLr = eL * cL, wLi = eL * sL;
    float fr = 0.f, fi = 0.f;
    for (int c = 0; c < NCH; c++) {
      float sr = Fb[c][2 * n], si = Fb[c][2 * n + 1];
      __builtin_amdgcn_sched_barrier(0);
      *(unsigned int*)&Fb[c][n] = packbf(fr, fi);       // incoming state for chunk c
      float nr = fmaf(wLr, fr, fmaf(-wLi, fi, sr));
      float ni = fmaf(wLr, fi, fmaf(wLi, fr, si));
      fr = nr; fi = ni;
    }
  }
  __syncthreads();

  // ---- phase 4: emit GEMM (M=32 c, N=128 j, K=192 [u|F]); wave wv owns j-tiles 2wv,2wv+1 ----
  f32x4 acc[2][2] = {};                     // [mt][ntl]
#pragma unroll
  for (int ksi = 0; ksi < 6; ksi++) {
    int kc = ksi * 32 + quad * 8;
    bf16x8 a2[2];
#pragma unroll
    for (int mt = 0; mt < 2; mt++)
      a2[mt] = (ksi < 4)
                 ? *(const bf16x8*)&Ub[mt * 16 + n16][kc]
                 : *(const bf16x8*)((const unsigned short*)&Fb[mt * 16 + n16][0] + (kc - 128));
#pragma unroll
    for (int ntl = 0; ntl < 2; ntl++) {
      int j = (wv * 2 + ntl) * 16 + n16;
      bf16x8 bv = (ksi < 4) ? *(const bf16x8*)&Tb[(h * 128 + j) * 128 + kc]
                            : *(const bf16x8*)&Eb[(h * 128 + j) * 64 + kc - 128];
#pragma unroll
      for (int mt = 0; mt < 2; mt++)
        acc[mt][ntl] = __builtin_amdgcn_mfma_f32_16x16x32_bf16(a2[mt], bv, acc[mt][ntl], 0, 0, 0);
    }
  }

  // ---- phase 5: epilogue — skip, tanh-GELU (== v*sigmoid(2t)), store bf16 ----
  float Dh = Dp[h];
  unsigned short* ybase = yb + (b * 256 + h) * 4096;
#pragma unroll
  for (int mt = 0; mt < 2; mt++) {
#pragma unroll
    for (int reg = 0; reg < 4; reg++) {
      int c = mt * 16 + quad * 4 + reg;
#pragma unroll
      for (int ntl = 0; ntl < 2; ntl++) {
        int j = (wv * 2 + ntl) * 16 + n16;
        float uv = bf2f(Ub[c][j]);
        float v  = fmaf(Dh, uv, acc[mt][ntl][reg]);
        // tanh-GELU: 0.5v(1+tanh(t)) = v*sigmoid(2t), t = 0.79788456*v*(1+0.044715 v^2)
        float t2 = 1.5957691216057308f * v * fmaf(0.044715f, v * v, 1.0f);
        float ge = v / (1.0f + expf(-t2));
        ybase[c * 128 + j] = f2bf(ge);
      }
    }
  }
}

// ---------------- K4: MFMA bf16 GEMM: z = W@y + b ; out = a * sigmoid(g) ----------------
// A-operand (W) read DIRECT from global per fragment (Wb 256KB, L2-resident, shared by
// all blocks on the XCD). Ys double-buffered; next K-step's y loads issued right after
// the barrier so HBM latency hides under MFMA; ONE barrier per K-step.
__global__ __launch_bounds__(256) void k_gemm(const unsigned short* __restrict__ yb,
                                              const unsigned short* __restrict__ Wb,
                                              const float* __restrict__ bias,
                                              float* __restrict__ out) {
  __shared__ unsigned short Ys[2][128][72];
  int tid  = threadIdx.x;
  int l0   = blockIdx.x * 128;
  int o0   = blockIdx.y * 64;
  int bb   = blockIdx.z;
  int wave = tid >> 6;
  int lane = tid & 63;
  int wo   = wave & 1;
  int wl   = wave >> 1;
  int n    = lane & 15;
  int quad = lane >> 4;
  int kcol = tid & 63;
  int lg0  = tid >> 6;

  f32x4 acc_a[2][4] = {};
  f32x4 acc_g[2][4] = {};

  u16x8 yreg[4];
  {
    const unsigned short* yr = yb + (size_t)(bb * 256 + kcol) * 4096 + l0;
#pragma unroll
    for (int i = 0; i < 4; i++)
      yreg[i] = *(const u16x8*)&yr[(lg0 * 4 + i) * 8];
  }

#pragma unroll
  for (int kk = 0; kk < H; kk += 64) {
    int cur = (kk >> 6) & 1;
    // transpose-write staged regs into Ys[cur]
#pragma unroll
    for (int i = 0; i < 4; i++) {
      int l8 = (lg0 * 4 + i) * 8;
#pragma unroll
      for (int jj = 0; jj < 8; jj++)
        Ys[cur][l8 + jj][kcol] = yreg[i][jj];
    }
    __syncthreads();
    // issue next K-step's y loads; latency hides under the MFMAs below
    if (kk + 64 < H) {
      const unsigned short* yr = yb + (size_t)(bb * 256 + kk + 64 + kcol) * 4096 + l0;
#pragma unroll
      for (int i = 0; i < 4; i++)
        yreg[i] = *(const u16x8*)&yr[(lg0 * 4 + i) * 8];
    }
#pragma unroll
    for (int ks = 0; ks < 64; ks += 32) {
      int kc = ks + quad * 8;
      bf16x8 af_a[2], af_g[2], bfr[4];
#pragma unroll
      for (int mt = 0; mt < 2; mt++) {
        int oa = o0 + wo * 32 + mt * 16 + n;
        af_a[mt] = *(const bf16x8*)&Wb[(size_t)oa * 256 + kk + kc];
        af_g[mt] = *(const bf16x8*)&Wb[(size_t)(256 + oa) * 256 + kk + kc];
      }
#pragma unroll
      for (int lt = 0; lt < 4; lt++)
        bfr[lt] = *(const bf16x8*)&Ys[cur][wl * 64 + lt * 16 + n][kc];
#pragma unroll
      for (int mt = 0; mt < 2; mt++)
#pragma unroll
        for (int lt = 0; lt < 4; lt++) {
          acc_a[mt][lt] = __builtin_amdgcn_mfma_f32_16x16x32_bf16(af_a[mt], bfr[lt], acc_a[mt][lt], 0, 0, 0);
          acc_g[mt][lt] = __builtin_amdgcn_mfma_f32_16x16x32_bf16(af_g[mt], bfr[lt], acc_g[mt][lt], 0, 0, 0);
        }
    }
  }
#pragma unroll
  for (int mt = 0; mt < 2; mt++) {
    int ob = o0 + wo * 32 + mt * 16 + quad * 4;
#pragma unroll
    for (int reg = 0; reg < 4; reg++) {
      int op = ob + reg;
      float ba = bias[op], bg = bias[H + op];
      float* orow = &out[(bb * H + op) * Lseq + l0 + wl * 64 + n];
#pragma unroll
      for (int lt = 0; lt < 4; lt++) {
        float a = acc_a[mt][lt][reg] + ba;
        float gg = acc_g[mt][lt][reg] + bg;
        orow[lt * 16] = a / (1.0f + expf(-gg));
      }
    }
  }
}

extern "C" void kernel_launch(void* const* d_in, const int* in_sizes, int n_in,
                              void* d_out, int out_size, void* d_ws, size_t ws_size,
                              hipStream_t stream) {
  const float* u      = (const float*)d_in[0];
  const float* log_dt = (const float*)d_in[1];
  const float* C      = (const float*)d_in[2];
  const float* lar    = (const float*)d_in[3];
  const float* aim    = (const float*)d_in[4];
  const float* Dp     = (const float*)d_in[5];
  const float* W      = (const float*)d_in[6];
  const float* bias   = (const float*)d_in[7];
  float* out = (float*)d_out;
  float* ws  = (float*)d_ws;
  unsigned short* yb  = (unsigned short*)(ws + Y_OFF);
  unsigned short* Wb  = (unsigned short*)(ws + WB_OFF);
  unsigned short* Tbg = (unsigned short*)(ws + TB_OFF);
  unsigned short* Ebg = (unsigned short*)(ws + EB_OFF);
  unsigned short* Vbg = (unsigned short*)(ws + VB_OFF);

  hipLaunchKernelGGL(k_prep, dim3(H), dim3(512), 0, stream, log_dt, C, lar, aim, W, Wb, Tbg, Ebg, Vbg);
  hipLaunchKernelGGL(k_ssm,  dim3(BH), dim3(256), 0, stream, u, log_dt, lar, aim, Vbg, Tbg, Ebg, Dp, yb);
  hipLaunchKernelGGL(k_gemm, dim3(Lseq / 128, H / 64, Bsz), dim3(256), 0, stream, yb, Wb, bias, out);
}

// Round 4
// 145.281 us; speedup vs baseline: 1.1572x; 1.0664x over previous
//
#include <hip/hip_runtime.h>
#include <math.h>

#define H 256
#define N2 32
#define Bsz 8
#define Lseq 4096
#define BH (Bsz*H)          // 2048 sequences
#define NCH 32              // chunks along L
#define LC (Lseq/NCH)       // 128 chunk length
#define HN (H*N2)           // 8192

// workspace layout (float slots):
//  yb : BH*Lseq bf16        post-GELU activations
//  Wb : 512*256 bf16        pre-converted W
//  Tb : H*128*128 bf16      Toeplitz conv matrix T[h][j][m] = k[h][j-m] (0 if j<m)
//  Eb : H*128*64 bf16       emission basis E[h][j][p]   (j-major, p-contig)
//  Vb : H*64*128 bf16       state basis  V[h][p][j]     (p-major, j-contig)
//  WL : H*64 f32            per-(h,n) chunk propagator wL = w^128 (re,im pairs)
#define Y_OFF  0
#define WB_OFF (Y_OFF + (BH*Lseq/2))
#define TB_OFF (WB_OFF + (512*256/2))
#define EB_OFF (TB_OFF + (H*128*128/2))
#define VB_OFF (EB_OFF + (H*128*64/2))
#define WL_OFF (VB_OFF + (H*64*128/2))

typedef __attribute__((ext_vector_type(8))) short bf16x8;
typedef __attribute__((ext_vector_type(8))) unsigned short u16x8;
typedef __attribute__((ext_vector_type(4))) float f32x4;

__device__ __forceinline__ unsigned short f2bf(float x) {
  union { float f; unsigned int u; } v; v.f = x;
  unsigned int r = v.u + 0x7fffu + ((v.u >> 16) & 1u);  // round-to-nearest-even
  return (unsigned short)(r >> 16);
}
__device__ __forceinline__ unsigned int packbf(float lo, float hi) {
  return (unsigned int)f2bf(lo) | ((unsigned int)f2bf(hi) << 16);
}
__device__ __forceinline__ float bf2f(unsigned short b) {
  union { unsigned int u; float f; } v; v.u = ((unsigned int)b) << 16;
  return v.f;
}

// ---------------- K0: prep — W->bf16, Toeplitz Tb, bases Eb & Vb, propagator WL ----------------
// grid 256 (h), block 512 = (j 0..127) x (ng 0..3); 8 waves/block = 2 waves/SIMD.
// All transcendentals via native v_exp/v_sin/v_cos (__expf/__sinf/__cosf): the ocml
// libcalls (sincosf with full-range reduction; args reach ~1240 rad) were the dominant
// instruction cost. fp32 arg-scaling error at 1240 rad ~1.5e-4 rad << bf16 quantum.
__global__ __launch_bounds__(512) void k_prep(const float* __restrict__ log_dt,
                                              const float* __restrict__ C,
                                              const float* __restrict__ lar,
                                              const float* __restrict__ aim,
                                              const float* __restrict__ W,
                                              unsigned short* __restrict__ Wb,
                                              unsigned short* __restrict__ Tb,
                                              unsigned short* __restrict__ Eb,
                                              unsigned short* __restrict__ Vb,
                                              float* __restrict__ WLb) {
  __shared__ float kpart[3][128];
  __shared__ unsigned short kbuf[128];
  int h   = blockIdx.x;
  int tid = threadIdx.x;
  int j   = tid & 127;                       // position in chunk
  int ng  = tid >> 7;                        // n-group {0..3}
  // ---- W fp32 -> bf16: threads 0..127 convert one float4 each ----
  if (tid < 128) {
    int i = h * 128 + tid;
    float4 v = *(const float4*)&W[i * 4];
    uint2 p; p.x = packbf(v.x, v.y); p.y = packbf(v.z, v.w);
    *(uint2*)&Wb[i * 4] = p;
  }
  float dt = __expf(log_dt[h]);
  float kacc = 0.f;
  unsigned short* Erow = Eb + (h * 128 + j) * 64;
  for (int nn = 0; nn < 8; nn++) {
    int n  = ng * 8 + nn;
    int hn = (h << 5) + n;
    float Ar = -__expf(lar[hn]), Ai = aim[hn];
    float dAr = Ar * dt, dAi = Ai * dt;
    float er = __expf(dAr);
    float sw = __sinf(dAi), cw = __cosf(dAi);
    float wr = er * cw, wi = er * sw;
    float emr = wr - 1.f, emi = wi;
    float inv = 1.f / (Ar * Ar + Ai * Ai);
    float qr = (emr * Ar + emi * Ai) * inv;
    float qi = (emi * Ar - emr * Ai) * inv;
    float Cr = C[2 * hn], Ci = C[2 * hn + 1];
    float c2r = 2.f * (Cr * qr - Ci * qi);    // 2*Ct
    float c2i = 2.f * (Cr * qi + Ci * qr);
    // k[j] += Re(2Ct * w^j)
    float ej = __expf(dAr * (float)j);
    float sj = __sinf(dAi * (float)j), cj = __cosf(dAi * (float)j);
    kacc = fmaf(c2r, ej * cj, fmaf(-c2i, ej * sj, kacc));
    // E[j][2n] = Re(2Ct w^{j+1}), E[j][2n+1] = -Im(2Ct w^{j+1})
    float e1 = __expf(dAr * (float)(j + 1));
    float s1 = __sinf(dAi * (float)(j + 1)), c1 = __cosf(dAi * (float)(j + 1));
    float w1r = e1 * c1, w1i = e1 * s1;
    Erow[2 * n]     = f2bf(c2r * w1r - c2i * w1i);
    Erow[2 * n + 1] = f2bf(-(c2r * w1i + c2i * w1r));
    // V[2n][j] = Re(w^{127-j}), V[2n+1][j] = Im(w^{127-j})
    float ev = __expf(dAr * (float)(127 - j));
    float sv = __sinf(dAi * (float)(127 - j)), cv = __cosf(dAi * (float)(127 - j));
    Vb[(h * 64 + 2 * n) * 128 + j]     = f2bf(ev * cv);
    Vb[(h * 64 + 2 * n + 1) * 128 + j] = f2bf(ev * sv);
    // chunk propagator wL = w^128 (one thread per n) -> removes ALL transcendentals
    // from k_ssm's serial prefix phase
    if (j == 0) {
      float eL = __expf(dAr * 128.f);
      float sL = __sinf(dAi * 128.f), cL = __cosf(dAi * 128.f);
      WLb[(h << 6) + 2 * n]     = eL * cL;
      WLb[(h << 6) + 2 * n + 1] = eL * sL;
    }
  }
  if (ng) kpart[ng - 1][j] = kacc;
  __syncthreads();
  if (ng == 0) kbuf[j] = f2bf(kacc + kpart[0][j] + kpart[1][j] + kpart[2][j]);
  __syncthreads();
  // Toeplitz row j: Tb[h][j][m] = kbuf[j-m] (j>=m) else 0; ng-groups split the 16 chunks
  unsigned short* Trow = Tb + (h * 128 + j) * 128;
#pragma unroll
  for (int s8i = 0; s8i < 4; s8i++) {
    int s8 = ng * 4 + s8i;
    u16x8 v;
#pragma unroll
    for (int t = 0; t < 8; t++) {
      int m = s8 * 8 + t;
      v[t] = (j >= m) ? kbuf[j - m] : (unsigned short)0;
    }
    *(u16x8*)&Trow[s8 * 8] = v;
  }
}

// ---------------- K1: fused SSM: states + prefix + emit, one block per (b,h) ----------------
// Block = 256 thr = 4 waves. R3 structure + (a) prefix propagator wL loaded from WLb
// (no transcendentals in the serial critical section), (b) triangular skip in the emit
// GEMM: Tb[j][m]=0 for m>j, so K-block ksi contributes to j-tile t only when
// 2*ksi <= t (wave-uniform branch, exact skip of 11/32 of T-MFMAs + their B-loads).
// XCD mapping: h = g & 255 => all 8 batch-copies of an h share an XCD; per-XCD
// T/E/V working set = 2MB (L2-resident, warm from k_prep).
__global__ __launch_bounds__(256, 8) void k_ssm(const float* __restrict__ u,
                                             const float* __restrict__ WLb,
                                             const unsigned short* __restrict__ Vb,
                                             const unsigned short* __restrict__ Tb,
                                             const unsigned short* __restrict__ Eb,
                                             const float* __restrict__ Dp,
                                             unsigned short* __restrict__ yb) {
  __shared__ __align__(16) unsigned short Ub[32][136];  // row stride 272 B (17*16)
  __shared__ __align__(16) float          Fb[32][68];   // fp32 chunk-final states;
                                                        // cols 0..31 become packed bf16
                                                        // incoming states after prefix
  int g   = blockIdx.x;
  int h   = g & 255, b = g >> 8;           // same-h blocks share an XCD -> T/E/V L2 reuse
  int tid = threadIdx.x;
  int wv = tid >> 6, lane = tid & 63;
  int n16 = lane & 15, quad = lane >> 4;
  const float* ubase = u + (b * 256 + h) * 4096;

  // ---- phase 1: stage u (coalesced float4 pairs -> bf16 LDS) ----
#pragma unroll
  for (int i = 0; i < 2; i++) {
    int idx = tid * 2 + i;                  // 0..511 float8s
    float4 va = *(const float4*)(ubase + idx * 8);
    float4 vb4 = *(const float4*)(ubase + idx * 8 + 4);
    unsigned short* dst = &Ub[idx >> 4][(idx & 15) * 8];
    *(unsigned int*)(dst)     = packbf(va.x, va.y);
    *(unsigned int*)(dst + 2) = packbf(va.z, va.w);
    *(unsigned int*)(dst + 4) = packbf(vb4.x, vb4.y);
    *(unsigned int*)(dst + 6) = packbf(vb4.z, vb4.w);
  }
  __syncthreads();

  // ---- phase 2: state GEMM (M=32 c, N=64 p, K=128 j); wave wv owns p-tile wv ----
  {
    f32x4 sacc[2] = {};
#pragma unroll
    for (int ks = 0; ks < 128; ks += 32) {
      int kc = ks + quad * 8;
      bf16x8 bv = *(const bf16x8*)&Vb[(h * 64 + wv * 16 + n16) * 128 + kc];
#pragma unroll
      for (int mt = 0; mt < 2; mt++) {
        bf16x8 av = *(const bf16x8*)&Ub[mt * 16 + n16][kc];
        sacc[mt] = __builtin_amdgcn_mfma_f32_16x16x32_bf16(av, bv, sacc[mt], 0, 0, 0);
      }
    }
#pragma unroll
    for (int mt = 0; mt < 2; mt++)
#pragma unroll
      for (int reg = 0; reg < 4; reg++)
        Fb[mt * 16 + quad * 4 + reg][wv * 16 + n16] = sacc[mt][reg];
  }
  __syncthreads();

  // ---- phase 3: serial prefix (wave 0, lane n = complex pair), packed IN PLACE ----
  // wL comes precomputed from WLb: the critical section is now 2 loads + the fmaf
  // chain. Reads fp32 state at cols {2n,2n+1}, then overwrites col n with the packed
  // bf16 incoming state (read precedes write in program order; per-wave in-order LDS;
  // sched_barrier(0) pins compiler order).
  if (wv == 0 && lane < 32) {
    int n = lane;
    float wLr = WLb[(h << 6) + 2 * n], wLi = WLb[(h << 6) + 2 * n + 1];
    float fr = 0.f, fi = 0.f;
    for (int c = 0; c < NCH; c++) {
      float sr = Fb[c][2 * n], si = Fb[c][2 * n + 1];
      __builtin_amdgcn_sched_barrier(0);
      *(unsigned int*)&Fb[c][n] = packbf(fr, fi);       // incoming state for chunk c
      float nr = fmaf(wLr, fr, fmaf(-wLi, fi, sr));
      float ni = fmaf(wLr, fi, fmaf(wLi, fr, si));
      fr = nr; fi = ni;
    }
  }
  __syncthreads();

  // ---- phase 4: emit GEMM (M=32 c, N=128 j, K=192 [u|F]); wave wv owns j-tiles 2wv,2wv+1 ----
  f32x4 acc[2][2] = {};                     // [mt][ntl]
#pragma unroll
  for (int ksi = 0; ksi < 6; ksi++) {
    int kc = ksi * 32 + quad * 8;
    bf16x8 a2[2];
#pragma unroll
    for (int mt = 0; mt < 2; mt++)
      a2[mt] = (ksi < 4)
                 ? *(const bf16x8*)&Ub[mt * 16 + n16][kc]
                 : *(const bf16x8*)((const unsigned short*)&Fb[mt * 16 + n16][0] + (kc - 128));
#pragma unroll
    for (int ntl = 0; ntl < 2; ntl++) {
      // triangular skip: K-block [32ksi, 32ksi+31] vs j-tile max 16(2wv+ntl)+15 —
      // entirely in the zero region iff 2*ksi > 2*wv+ntl (exact; wave-uniform).
      if (ksi < 4 && 2 * ksi > 2 * wv + ntl) continue;
      int j = (wv * 2 + ntl) * 16 + n16;
      bf16x8 bv = (ksi < 4) ? *(const bf16x8*)&Tb[(h * 128 + j) * 128 + kc]
                            : *(const bf16x8*)&Eb[(h * 128 + j) * 64 + kc - 128];
#pragma unroll
      for (int mt = 0; mt < 2; mt++)
        acc[mt][ntl] = __builtin_amdgcn_mfma_f32_16x16x32_bf16(a2[mt], bv, acc[mt][ntl], 0, 0, 0);
    }
  }

  // ---- phase 5: epilogue — skip, tanh-GELU (== v*sigmoid(2t)), store bf16 ----
  float Dh = Dp[h];
  unsigned short* ybase = yb + (b * 256 + h) * 4096;
#pragma unroll
  for (int mt = 0; mt < 2; mt++) {
#pragma unroll
    for (int reg = 0; reg < 4; reg++) {
      int c = mt * 16 + quad * 4 + reg;
#pragma unroll
      for (int ntl = 0; ntl < 2; ntl++) {
        int j = (wv * 2 + ntl) * 16 + n16;
        float uv = bf2f(Ub[c][j]);
        float v  = fmaf(Dh, uv, acc[mt][ntl][reg]);
        // tanh-GELU: 0.5v(1+tanh(t)) = v*sigmoid(2t), t = 0.79788456*v*(1+0.044715 v^2)
        float t2 = 1.5957691216057308f * v * fmaf(0.044715f, v * v, 1.0f);
        float ge = v / (1.0f + __expf(-t2));
        ybase[c * 128 + j] = f2bf(ge);
      }
    }
  }
}

// ---------------- K4: MFMA bf16 GEMM: z = W@y + b ; out = a * sigmoid(g) ----------------
// A-operand (W) read DIRECT from global per fragment (Wb 256KB, L2-resident, shared by
// all blocks on the XCD). Ys double-buffered; next K-step's y loads issued right after
// the barrier so latency hides under MFMA; ONE barrier per K-step.
// Staging transposes via k-PAIRED u32 stores (16 dword stores vs 32 b16 stores):
// thread owns rows (k0,k0+1) x 16 l's; store (y[k0][l],y[k0+1][l]) as one u32 to
// Ys[l][k0]. Bank check: lanes 0..31 hit 32 distinct banks; lanes 32..63 alias them
// 2-way (free).
__global__ __launch_bounds__(256) void k_gemm(const unsigned short* __restrict__ yb,
                                              const unsigned short* __restrict__ Wb,
                                              const float* __restrict__ bias,
                                              float* __restrict__ out) {
  __shared__ unsigned short Ys[2][128][72];
  int tid  = threadIdx.x;
  int l0   = blockIdx.x * 128;
  int o0   = blockIdx.y * 64;
  int bb   = blockIdx.z;
  int wave = tid >> 6;
  int lane = tid & 63;
  int wo   = wave & 1;
  int wl   = wave >> 1;
  int n    = lane & 15;
  int quad = lane >> 4;
  int kp   = (tid & 31) * 2;     // k-pair base: 0,2,..,62
  int lg   = tid >> 5;           // l-group 0..7 (16 l's each)

  f32x4 acc_a[2][4] = {};
  f32x4 acc_g[2][4] = {};

  u16x8 y0a, y0b, y1a, y1b;      // rows kp, kp+1 at l = lg*16..lg*16+15
  {
    const unsigned short* yr = yb + (size_t)(bb * 256 + kp) * 4096 + l0 + lg * 16;
    y0a = *(const u16x8*)&yr[0];     y0b = *(const u16x8*)&yr[8];
    y1a = *(const u16x8*)&yr[4096];  y1b = *(const u16x8*)&yr[4096 + 8];
  }

#pragma unroll
  for (int kk = 0; kk < H; kk += 64) {
    int cur = (kk >> 6) & 1;
    // k-paired transpose-write into Ys[cur]
#pragma unroll
    for (int t = 0; t < 8; t++) {
      *(unsigned int*)&Ys[cur][lg * 16 + t][kp] =
          (unsigned int)(unsigned short)y0a[t] | ((unsigned int)(unsigned short)y1a[t] << 16);
      *(unsigned int*)&Ys[cur][lg * 16 + 8 + t][kp] =
          (unsigned int)(unsigned short)y0b[t] | ((unsigned int)(unsigned short)y1b[t] << 16);
    }
    __syncthreads();
    // issue next K-step's y loads; latency hides under the MFMAs below
    if (kk + 64 < H) {
      const unsigned short* yr = yb + (size_t)(bb * 256 + kk + 64 + kp) * 4096 + l0 + lg * 16;
      y0a = *(const u16x8*)&yr[0];     y0b = *(const u16x8*)&yr[8];
      y1a = *(const u16x8*)&yr[4096];  y1b = *(const u16x8*)&yr[4096 + 8];
    }
#pragma unroll
    for (int ks = 0; ks < 64; ks += 32) {
      int kc = ks + quad * 8;
      bf16x8 af_a[2], af_g[2], bfr[4];
#pragma unroll
      for (int mt = 0; mt < 2; mt++) {
        int oa = o0 + wo * 32 + mt * 16 + n;
        af_a[mt] = *(const bf16x8*)&Wb[(size_t)oa * 256 + kk + kc];
        af_g[mt] = *(const bf16x8*)&Wb[(size_t)(256 + oa) * 256 + kk + kc];
      }
#pragma unroll
      for (int lt = 0; lt < 4; lt++)
        bfr[lt] = *(const bf16x8*)&Ys[cur][wl * 64 + lt * 16 + n][kc];
#pragma unroll
      for (int mt = 0; mt < 2; mt++)
#pragma unroll
        for (int lt = 0; lt < 4; lt++) {
          acc_a[mt][lt] = __builtin_amdgcn_mfma_f32_16x16x32_bf16(af_a[mt], bfr[lt], acc_a[mt][lt], 0, 0, 0);
          acc_g[mt][lt] = __builtin_amdgcn_mfma_f32_16x16x32_bf16(af_g[mt], bfr[lt], acc_g[mt][lt], 0, 0, 0);
        }
    }
  }
#pragma unroll
  for (int mt = 0; mt < 2; mt++) {
    int ob = o0 + wo * 32 + mt * 16 + quad * 4;
#pragma unroll
    for (int reg = 0; reg < 4; reg++) {
      int op = ob + reg;
      float ba = bias[op], bg = bias[H + op];
      float* orow = &out[(bb * H + op) * Lseq + l0 + wl * 64 + n];
#pragma unroll
      for (int lt = 0; lt < 4; lt++) {
        float a = acc_a[mt][lt][reg] + ba;
        float gg = acc_g[mt][lt][reg] + bg;
        orow[lt * 16] = a / (1.0f + __expf(-gg));
      }
    }
  }
}

extern "C" void kernel_launch(void* const* d_in, const int* in_sizes, int n_in,
                              void* d_out, int out_size, void* d_ws, size_t ws_size,
                              hipStream_t stream) {
  const float* u      = (const float*)d_in[0];
  const float* log_dt = (const float*)d_in[1];
  const float* C      = (const float*)d_in[2];
  const float* lar    = (const float*)d_in[3];
  const float* aim    = (const float*)d_in[4];
  const float* Dp     = (const float*)d_in[5];
  const float* W      = (const float*)d_in[6];
  const float* bias   = (const float*)d_in[7];
  float* out = (float*)d_out;
  float* ws  = (float*)d_ws;
  unsigned short* yb  = (unsigned short*)(ws + Y_OFF);
  unsigned short* Wb  = (unsigned short*)(ws + WB_OFF);
  unsigned short* Tbg = (unsigned short*)(ws + TB_OFF);
  unsigned short* Ebg = (unsigned short*)(ws + EB_OFF);
  unsigned short* Vbg = (unsigned short*)(ws + VB_OFF);
  float*          WLb = (float*)(ws + WL_OFF);

  hipLaunchKernelGGL(k_prep, dim3(H), dim3(512), 0, stream, log_dt, C, lar, aim, W, Wb, Tbg, Ebg, Vbg, WLb);
  hipLaunchKernelGGL(k_ssm,  dim3(BH), dim3(256), 0, stream, u, WLb, Vbg, Tbg, Ebg, Dp, yb);
  hipLaunchKernelGGL(k_gemm, dim3(Lseq / 128, H / 64, Bsz), dim3(256), 0, stream, yb, Wb, bias, out);
}